// Round 6
// baseline (289.185 us; speedup 1.0000x reference)
//
#include <hip/hip_runtime.h>
#include <hip/hip_bf16.h>
#include <math.h>

#define H 1024
#define R 64
#define NTHREADS 256
#define ROWS_PER_WAVE 16
#define ROWS_PER_BLOCK 64
#define TSTRIDE 72   // per-wave t buffer row stride (shorts): 144B, 2-way banks only

typedef __attribute__((ext_vector_type(8))) short short8;
typedef __attribute__((ext_vector_type(4))) float floatx4;

__device__ __forceinline__ unsigned short f2bf(float f) {
    unsigned int u = __builtin_bit_cast(unsigned int, f);
    u += 0x7fffu + ((u >> 16) & 1u);   // round-to-nearest-even
    return (unsigned short)(u >> 16);
}

// ---- prep: weights -> bf16 MFMA B-fragments (gamma folded into W_down) ----
// frag f, lane l, elem j -> ws[(f*64+l)*8+j]; k = (l>>4)*8 + j within k-tile
__global__ void prep_weights(const float* __restrict__ w_down,
                             const float* __restrict__ w_up,
                             const float* __restrict__ gamma,
                             unsigned short* __restrict__ wsd,
                             unsigned short* __restrict__ wsu) {
    int tid = blockIdx.x * blockDim.x + threadIdx.x;   // 0..65535
    int j    = tid & 7;
    int lane = (tid >> 3) & 63;
    int f    = tid >> 9;                               // 0..127
    int b = lane >> 4, p = lane & 15;
    {   // W' = gamma * W_down: f = kk*4 + n
        int kk = f >> 2, n = f & 3;
        int row = kk * 32 + b * 8 + j;
        int col = n * 16 + p;
        wsd[tid] = f2bf(gamma[row] * w_down[row * R + col]);
    }
    {   // W_up: f = ks*64 + n
        int ks = f >> 6, n = f & 63;
        int row = ks * 32 + b * 8 + j;
        int col = n * 16 + p;
        wsu[tid] = f2bf(w_up[row * H + col]);
    }
}

// ---- prep: w1[r] = sum_h gamma[h]*W_down[h][r]; c0[r] = sum_h beta[h]*W_down[h][r] + b_down[r]
__global__ void prep_vec(const float* __restrict__ w_down,
                         const float* __restrict__ gamma,
                         const float* __restrict__ beta,
                         const float* __restrict__ b_down,
                         float* __restrict__ w1, float* __restrict__ c0) {
    int r = blockIdx.x;          // 0..63
    int t = threadIdx.x;         // 256 threads
    float a = 0.f, c = 0.f;
    for (int h = t; h < H; h += NTHREADS) {
        float wd = w_down[h * R + r];
        a += gamma[h] * wd;
        c += beta[h] * wd;
    }
    #pragma unroll
    for (int off = 32; off >= 1; off >>= 1) {
        a += __shfl_xor(a, off);
        c += __shfl_xor(c, off);
    }
    __shared__ float red[8];
    int wv = t >> 6;
    if ((t & 63) == 0) { red[wv] = a; red[4 + wv] = c; }
    __syncthreads();
    if (t == 0) {
        w1[r] = red[0] + red[1] + red[2] + red[3];
        c0[r] = red[4] + red[5] + red[6] + red[7] + b_down[r];
    }
}

// Fully wave-local: each wave owns 16 rows end-to-end. One barrier per block
// (LDS transpose of t). No inter-wave data exchange.
__global__ __launch_bounds__(NTHREADS, 4)
void adapter_kernel(const float* __restrict__ x,
                    const float* __restrict__ b_up,
                    const unsigned short* __restrict__ wsd,
                    const unsigned short* __restrict__ wsu,
                    const float* __restrict__ w1v,
                    const float* __restrict__ c0v,
                    float* __restrict__ out) {
    __shared__ __align__(16) unsigned short t_lds[4][ROWS_PER_WAVE * TSTRIDE]; // 9 KB

    const int tid  = threadIdx.x;
    const int lane = tid & 63;
    const int w    = tid >> 6;
    const int p    = lane & 15;
    const int b    = lane >> 4;
    const long row0 = (long)blockIdx.x * ROWS_PER_BLOCK + w * ROWS_PER_WAVE;

    // ---- down-proj: x (global, frag layout) -> acc[4]; stats on the fly ----
    float s1 = 0.f, s2 = 0.f;               // lane accumulates row p, k = kt*32+b*8+e
    floatx4 acc[4];
    #pragma unroll
    for (int nt = 0; nt < 4; ++nt) acc[nt] = floatx4{0.f, 0.f, 0.f, 0.f};

    const short8* wsd8 = (const short8*)wsd;
    const float* xw = x + (row0 + p) * H + b * 8;
    #pragma unroll 4
    for (int kt = 0; kt < 32; ++kt) {
        floatx4 v0 = *(const floatx4*)(xw + kt * 32);
        floatx4 v1 = *(const floatx4*)(xw + kt * 32 + 4);
        short8 a;
        #pragma unroll
        for (int e = 0; e < 4; ++e) {
            s1 += v0[e] + v1[e];
            s2 += v0[e] * v0[e] + v1[e] * v1[e];
            a[e]     = (short)f2bf(v0[e]);
            a[4 + e] = (short)f2bf(v1[e]);
        }
        #pragma unroll
        for (int nt = 0; nt < 4; ++nt)
            acc[nt] = __builtin_amdgcn_mfma_f32_16x16x32_bf16(a, wsd8[(size_t)(kt * 4 + nt) * 64 + lane], acc[nt], 0, 0, 0);
    }

    // ---- row stats: reduce over b (shfl 16,32); lane ends with row-p mu/rs ----
    s1 += __shfl_xor(s1, 16); s1 += __shfl_xor(s1, 32);
    s2 += __shfl_xor(s2, 16); s2 += __shfl_xor(s2, 32);
    float mu = s1 * (1.0f / (float)H);
    float var = s2 * (1.0f / (float)H) - mu * mu;
    float rs = rsqrtf(var + 1e-5f);

    // ---- folded LN + GELU; write t (C/D rows b*4+reg) to wave-private LDS ----
    #pragma unroll
    for (int reg = 0; reg < 4; ++reg) {
        float mur = __shfl(mu, b * 4 + reg);     // row (b*4+reg) stats live at lane p==b*4+reg
        float rsr = __shfl(rs, b * 4 + reg);
        #pragma unroll
        for (int nt = 0; nt < 4; ++nt) {
            int col = nt * 16 + p;
            float u = rsr * (acc[nt][reg] - mur * w1v[col]) + c0v[col];
            u = 0.5f * u * (1.0f + erff(u * 0.70710678f));
            t_lds[w][(b * 4 + reg) * TSTRIDE + col] = f2bf(u);
        }
    }
    __syncthreads();   // cross-lane LDS visibility (single barrier in kernel)

    // ---- up-proj: A-frags from t (rows p, k = b*8+j), B from wsu; +residual ----
    short8 a0 = *(const short8*)&t_lds[w][p * TSTRIDE + b * 8];        // k 0..31
    short8 a1 = *(const short8*)&t_lds[w][p * TSTRIDE + 32 + b * 8];   // k 32..63
    const short8* wsu8 = (const short8*)wsu;
    const long rbase = row0 + b * 4;

    #pragma unroll 4
    for (int n = 0; n < 64; ++n) {
        short8 bu0 = wsu8[(size_t)n * 64 + lane];
        short8 bu1 = wsu8[(size_t)(64 + n) * 64 + lane];
        floatx4 av = {0.f, 0.f, 0.f, 0.f};
        av = __builtin_amdgcn_mfma_f32_16x16x32_bf16(a0, bu0, av, 0, 0, 0);
        av = __builtin_amdgcn_mfma_f32_16x16x32_bf16(a1, bu1, av, 0, 0, 0);
        int col = n * 16 + p;
        float bup = b_up[col];
        #pragma unroll
        for (int reg = 0; reg < 4; ++reg) {
            long rr = rbase + reg;
            out[rr * H + col] = av[reg] + bup + x[rr * H + col];
        }
    }
}

extern "C" void kernel_launch(void* const* d_in, const int* in_sizes, int n_in,
                              void* d_out, int out_size, void* d_ws, size_t ws_size,
                              hipStream_t stream) {
    const float* x      = (const float*)d_in[0];
    const float* gamma  = (const float*)d_in[1];
    const float* beta   = (const float*)d_in[2];
    const float* w_down = (const float*)d_in[3];
    const float* b_down = (const float*)d_in[4];
    const float* w_up   = (const float*)d_in[5];
    const float* b_up   = (const float*)d_in[6];
    float* out = (float*)d_out;

    unsigned short* wsd = (unsigned short*)d_ws;
    unsigned short* wsu = wsd + 65536;
    float* w1 = (float*)(wsu + 65536);
    float* c0 = w1 + 64;

    int M = in_sizes[0] / H;                 // 32768 rows
    prep_weights<<<256, 256, 0, stream>>>(w_down, w_up, gamma, wsd, wsu);
    prep_vec<<<64, 256, 0, stream>>>(w_down, gamma, beta, b_down, w1, c0);
    adapter_kernel<<<M / ROWS_PER_BLOCK, NTHREADS, 0, stream>>>(x, b_up, wsd, wsu, w1, c0, out);
}

// Round 7
// 278.216 us; speedup vs baseline: 1.0394x; 1.0394x over previous
//
#include <hip/hip_runtime.h>
#include <hip/hip_bf16.h>
#include <math.h>

#define H 1024
#define R 64
#define NTHREADS 256
#define TSTRIDE 72   // t buffer row stride (shorts): 144B, benign banks

typedef __attribute__((ext_vector_type(8))) short short8;
typedef __attribute__((ext_vector_type(4))) float floatx4;

__device__ __forceinline__ unsigned short f2bf(float f) {
    unsigned int u = __builtin_bit_cast(unsigned int, f);
    u += 0x7fffu + ((u >> 16) & 1u);   // round-to-nearest-even
    return (unsigned short)(u >> 16);
}

// ---- single prep kernel: blocks 0..255 pack weight frags; 256..319 colsums ----
// frag f, lane l, elem j -> ws[(f*64+l)*8+j]; k = (l>>4)*8 + j within k-tile
__global__ void prep(const float* __restrict__ w_down,
                     const float* __restrict__ w_up,
                     const float* __restrict__ gamma,
                     const float* __restrict__ beta,
                     const float* __restrict__ b_down,
                     unsigned short* __restrict__ wsd,
                     unsigned short* __restrict__ wsu,
                     float* __restrict__ w1, float* __restrict__ c0) {
    __shared__ float red[8];
    int bid = blockIdx.x;
    if (bid < 256) {
        int tid = bid * NTHREADS + threadIdx.x;        // 0..65535
        int j    = tid & 7;
        int lane = (tid >> 3) & 63;
        int f    = tid >> 9;                           // 0..127
        int b = lane >> 4, p = lane & 15;
        {   // W' = gamma * W_down: f = kk*4 + n
            int kk = f >> 2, n = f & 3;
            int row = kk * 32 + b * 8 + j;
            int col = n * 16 + p;
            wsd[tid] = f2bf(gamma[row] * w_down[row * R + col]);
        }
        {   // W_up: f = ks*64 + n
            int ks = f >> 6, n = f & 63;
            int row = ks * 32 + b * 8 + j;
            int col = n * 16 + p;
            wsu[tid] = f2bf(w_up[row * H + col]);
        }
    } else {
        // w1[r] = sum_h gamma[h]*W_down[h][r]; c0[r] = sum_h beta[h]*W_down[h][r] + b_down[r]
        int r = bid - 256;                 // 0..63
        int t = threadIdx.x;
        float a = 0.f, c = 0.f;
        for (int h = t; h < H; h += NTHREADS) {
            float wd = w_down[h * R + r];
            a += gamma[h] * wd;
            c += beta[h] * wd;
        }
        #pragma unroll
        for (int off = 32; off >= 1; off >>= 1) {
            a += __shfl_xor(a, off);
            c += __shfl_xor(c, off);
        }
        int wv = t >> 6;
        if ((t & 63) == 0) { red[wv] = a; red[4 + wv] = c; }
        __syncthreads();
        if (t == 0) {
            w1[r] = red[0] + red[1] + red[2] + red[3];
            c0[r] = red[4] + red[5] + red[6] + red[7] + b_down[r];
        }
    }
}

// Wave-local 16 rows end-to-end; deep explicit prefetch for memory-level
// parallelism (grid caps residency at 8 waves/CU, so per-wave ILP is the
// only latency lever).
__global__ __launch_bounds__(NTHREADS, 2)
void adapter_kernel(const float* __restrict__ x,
                    const float* __restrict__ b_up,
                    const unsigned short* __restrict__ wsd,
                    const unsigned short* __restrict__ wsu,
                    const float* __restrict__ w1v,
                    const float* __restrict__ c0v,
                    float* __restrict__ out) {
    __shared__ __align__(16) unsigned short t_lds[4][16 * TSTRIDE]; // 9 KB

    const int tid  = threadIdx.x;
    const int lane = tid & 63;
    const int w    = tid >> 6;
    const int p    = lane & 15;
    const int b    = lane >> 4;
    const long row0 = (long)blockIdx.x * 64 + w * 16;

    // ================= down-proj: rolling 8-deep x prefetch ================
    float s1 = 0.f, s2 = 0.f;           // lane: row p, k = kt*32 + b*8 + e
    floatx4 acc[4];
    #pragma unroll
    for (int nt = 0; nt < 4; ++nt) acc[nt] = floatx4{0.f, 0.f, 0.f, 0.f};

    const float* xw = x + (row0 + p) * H + b * 8;
    const short8* wsd8 = (const short8*)wsd;

    floatx4 bx0[8], bx1[8];             // 8-deep x prefetch (16 loads in flight)
    short8 wd[2][4];                    // 2-deep W_down frag prefetch
    #pragma unroll
    for (int i = 0; i < 8; ++i) {
        bx0[i] = *(const floatx4*)(xw + i * 32);
        bx1[i] = *(const floatx4*)(xw + i * 32 + 4);
    }
    #pragma unroll
    for (int nt = 0; nt < 4; ++nt) {
        wd[0][nt] = wsd8[(size_t)nt * 64 + lane];
        wd[1][nt] = wsd8[(size_t)(4 + nt) * 64 + lane];
    }

    for (int ko = 0; ko < 3; ++ko) {            // main groups: kt 0..23
        #pragma unroll
        for (int ki = 0; ki < 8; ++ki) {
            const int kt = ko * 8 + ki;
            floatx4 v0 = bx0[ki], v1 = bx1[ki];
            bx0[ki] = *(const floatx4*)(xw + (kt + 8) * 32);
            bx1[ki] = *(const floatx4*)(xw + (kt + 8) * 32 + 4);
            short8 wl[4];
            #pragma unroll
            for (int nt = 0; nt < 4; ++nt) {
                wl[nt] = wd[ki & 1][nt];
                wd[ki & 1][nt] = wsd8[(size_t)((kt + 2) * 4 + nt) * 64 + lane];
            }
            short8 a;
            #pragma unroll
            for (int e = 0; e < 4; ++e) {
                s1 += v0[e] + v1[e];
                s2 += v0[e] * v0[e] + v1[e] * v1[e];
                a[e]     = (short)f2bf(v0[e]);
                a[4 + e] = (short)f2bf(v1[e]);
            }
            #pragma unroll
            for (int nt = 0; nt < 4; ++nt)
                acc[nt] = __builtin_amdgcn_mfma_f32_16x16x32_bf16(a, wl[nt], acc[nt], 0, 0, 0);
        }
    }
    #pragma unroll
    for (int ki = 0; ki < 8; ++ki) {            // tail: kt 24..31
        const int kt = 24 + ki;
        floatx4 v0 = bx0[ki], v1 = bx1[ki];
        short8 wl[4];
        #pragma unroll
        for (int nt = 0; nt < 4; ++nt) {
            wl[nt] = wd[ki & 1][nt];
            if (ki < 6)
                wd[ki & 1][nt] = wsd8[(size_t)((kt + 2) * 4 + nt) * 64 + lane];
        }
        short8 a;
        #pragma unroll
        for (int e = 0; e < 4; ++e) {
            s1 += v0[e] + v1[e];
            s2 += v0[e] * v0[e] + v1[e] * v1[e];
            a[e]     = (short)f2bf(v0[e]);
            a[4 + e] = (short)f2bf(v1[e]);
        }
        #pragma unroll
        for (int nt = 0; nt < 4; ++nt)
            acc[nt] = __builtin_amdgcn_mfma_f32_16x16x32_bf16(a, wl[nt], acc[nt], 0, 0, 0);
    }

    // ---- row stats (reduce over b), folded LN + GELU, t -> wave LDS ------
    s1 += __shfl_xor(s1, 16); s1 += __shfl_xor(s1, 32);
    s2 += __shfl_xor(s2, 16); s2 += __shfl_xor(s2, 32);
    float mu = s1 * (1.0f / (float)H);
    float var = s2 * (1.0f / (float)H) - mu * mu;
    float rs = rsqrtf(var + 1e-5f);

    #pragma unroll
    for (int reg = 0; reg < 4; ++reg) {
        float mur = __shfl(mu, b * 4 + reg);
        float rsr = __shfl(rs, b * 4 + reg);
        #pragma unroll
        for (int nt = 0; nt < 4; ++nt) {
            int col = nt * 16 + p;
            float u = rsr * (acc[nt][reg] - mur * w1v[col]) + c0v[col];
            u = 0.5f * u * (1.0f + erff(u * 0.70710678f));
            t_lds[w][(b * 4 + reg) * TSTRIDE + col] = f2bf(u);
        }
    }

    // ============ up-proj prologue: issue prefetch BEFORE the barrier ======
    const short8* wsu8 = (const short8*)wsu;
    const long rbase = row0 + b * 4;
    short8 wq0[8], wq1[8];              // 8-deep W_up frag prefetch
    float bb[8], rx0[8], rx1[8], rx2[8], rx3[8];   // bias + residual prefetch
    #pragma unroll
    for (int i = 0; i < 8; ++i) {
        wq0[i] = wsu8[(size_t)i * 64 + lane];
        wq1[i] = wsu8[(size_t)(64 + i) * 64 + lane];
        int col = i * 16 + p;
        bb[i]  = b_up[col];
        rx0[i] = x[(rbase + 0) * H + col];
        rx1[i] = x[(rbase + 1) * H + col];
        rx2[i] = x[(rbase + 2) * H + col];
        rx3[i] = x[(rbase + 3) * H + col];
    }
    __syncthreads();
    short8 a0 = *(const short8*)&t_lds[w][p * TSTRIDE + b * 8];        // k 0..31
    short8 a1 = *(const short8*)&t_lds[w][p * TSTRIDE + 32 + b * 8];   // k 32..63

    // ============ up-proj main loop: rolling 8-deep everything =============
    for (int no = 0; no < 7; ++no) {
        #pragma unroll
        for (int ni = 0; ni < 8; ++ni) {
            const int n = no * 8 + ni;
            short8 bu0 = wq0[ni], bu1 = wq1[ni];
            float bup = bb[ni];
            float r0 = rx0[ni], r1 = rx1[ni], r2 = rx2[ni], r3 = rx3[ni];
            const int nc = n + 8;
            const int colc = nc * 16 + p;
            wq0[ni] = wsu8[(size_t)nc * 64 + lane];
            wq1[ni] = wsu8[(size_t)(64 + nc) * 64 + lane];
            bb[ni]  = b_up[colc];
            rx0[ni] = x[(rbase + 0) * H + colc];
            rx1[ni] = x[(rbase + 1) * H + colc];
            rx2[ni] = x[(rbase + 2) * H + colc];
            rx3[ni] = x[(rbase + 3) * H + colc];
            floatx4 av = {0.f, 0.f, 0.f, 0.f};
            av = __builtin_amdgcn_mfma_f32_16x16x32_bf16(a0, bu0, av, 0, 0, 0);
            av = __builtin_amdgcn_mfma_f32_16x16x32_bf16(a1, bu1, av, 0, 0, 0);
            const int col = n * 16 + p;
            out[(rbase + 0) * H + col] = av[0] + bup + r0;
            out[(rbase + 1) * H + col] = av[1] + bup + r1;
            out[(rbase + 2) * H + col] = av[2] + bup + r2;
            out[(rbase + 3) * H + col] = av[3] + bup + r3;
        }
    }
    #pragma unroll
    for (int ni = 0; ni < 8; ++ni) {            // tail: n 56..63, consume only
        const int n = 56 + ni;
        short8 bu0 = wq0[ni], bu1 = wq1[ni];
        floatx4 av = {0.f, 0.f, 0.f, 0.f};
        av = __builtin_amdgcn_mfma_f32_16x16x32_bf16(a0, bu0, av, 0, 0, 0);
        av = __builtin_amdgcn_mfma_f32_16x16x32_bf16(a1, bu1, av, 0, 0, 0);
        const int col = n * 16 + p;
        out[(rbase + 0) * H + col] = av[0] + bb[ni] + rx0[ni];
        out[(rbase + 1) * H + col] = av[1] + bb[ni] + rx1[ni];
        out[(rbase + 2) * H + col] = av[2] + bb[ni] + rx2[ni];
        out[(rbase + 3) * H + col] = av[3] + bb[ni] + rx3[ni];
    }
}

extern "C" void kernel_launch(void* const* d_in, const int* in_sizes, int n_in,
                              void* d_out, int out_size, void* d_ws, size_t ws_size,
                              hipStream_t stream) {
    const float* x      = (const float*)d_in[0];
    const float* gamma  = (const float*)d_in[1];
    const float* beta   = (const float*)d_in[2];
    const float* w_down = (const float*)d_in[3];
    const float* b_down = (const float*)d_in[4];
    const float* w_up   = (const float*)d_in[5];
    const float* b_up   = (const float*)d_in[6];
    float* out = (float*)d_out;

    unsigned short* wsd = (unsigned short*)d_ws;
    unsigned short* wsu = wsd + 65536;
    float* w1 = (float*)(wsu + 65536);
    float* c0 = w1 + 64;

    int M = in_sizes[0] / H;                 // 32768 rows
    prep<<<320, NTHREADS, 0, stream>>>(w_down, w_up, gamma, beta, b_down,
                                       wsd, wsu, w1, c0);
    adapter_kernel<<<M / 64, NTHREADS, 0, stream>>>(x, b_up, wsd, wsu, w1, c0, out);
}